// Round 20
// baseline (70.877 us; speedup 1.0000x reference)
//
#include <hip/hip_runtime.h>
#include <hip/hip_bf16.h>

#define N_ROWS 8192
#define DIM 256
#define TEMP_INV 20.0f
// logit2 = cos * 20*log2(e); with int8 quantized (x127) operands the exact
// i32 dot is converted via C2F = 20*log2(e)/127^2, then exp2.
#define C2F 1.7889516e-3f

typedef __attribute__((ext_vector_type(4))) int i32x4;
typedef __attribute__((ext_vector_type(16))) int i32x16;

// ---------------------------------------------------------------------------
// 1) Merged prep (int8 quantization) -- unchanged from R13/R16/R19 (proven).
// ---------------------------------------------------------------------------
__global__ void __launch_bounds__(256) prep_kernel(
    const float* __restrict__ anc, const float* __restrict__ pos,
    const float* __restrict__ neg, char* __restrict__ a8,
    char* __restrict__ p8, char* __restrict__ n8,
    float* __restrict__ diag, float* __restrict__ rowsum,
    float* __restrict__ out) {
  __shared__ __align__(16) char t8[8192];   // one k-major i8 panel
  const int lane = threadIdx.x & 63;
  const int w = threadIdx.x >> 6;

  if (blockIdx.x < 2048) {                   // ---- anchor rows ----
    int wid = blockIdx.x * 4 + w;            // row 0..8191
    float4 a = reinterpret_cast<const float4*>(anc + (size_t)wid * DIM)[lane];
    float4 p = reinterpret_cast<const float4*>(pos + (size_t)wid * DIM)[lane];
    float d  = a.x * p.x + a.y * p.y + a.z * p.z + a.w * p.w;
    float na = a.x * a.x + a.y * a.y + a.z * a.z + a.w * a.w;
    float np = p.x * p.x + p.y * p.y + p.z * p.z + p.w * p.w;
#pragma unroll
    for (int m = 32; m; m >>= 1) {
      d  += __shfl_xor(d, m);
      na += __shfl_xor(na, m);
      np += __shfl_xor(np, m);
    }
    float rna = fmaxf(sqrtf(na), 1e-8f);
    float s = 127.0f / rna;
    int q0 = (int)rintf(a.x * s), q1 = (int)rintf(a.y * s);
    int q2 = (int)rintf(a.z * s), q3 = (int)rintf(a.w * s);
    unsigned pk = (q0 & 0xFF) | ((q1 & 0xFF) << 8) |
                  ((q2 & 0xFF) << 16) | ((q3 & 0xFF) << 24);
    *reinterpret_cast<unsigned*>(a8 + (size_t)wid * DIM + (lane << 2)) = pk;
    if (lane == 0) {
      diag[wid] = TEMP_INV * d / (rna * fmaxf(sqrtf(np), 1e-8f));
      rowsum[wid] = 0.f;
    }
    return;
  }
  // ---- P/N k-major i8 panels ----
  const int b = blockIdx.x - 2048;           // 0..511
  if (b == 511 && threadIdx.x == 0) out[0] = 0.f;
  const float* src = (b < 256) ? pos : neg;
  char* dst = (b < 256) ? p8 : n8;
  const int pb = b & 255;
#pragma unroll
  for (int i = 0; i < 8; ++i) {
    int r = i * 4 + w;                       // row (col of B) within panel
    float4 v = reinterpret_cast<const float4*>(src + (size_t)(pb * 32 + r) * DIM)[lane];
    float ss = v.x * v.x + v.y * v.y + v.z * v.z + v.w * v.w;
#pragma unroll
    for (int m = 32; m; m >>= 1) ss += __shfl_xor(ss, m);
    float s = 127.0f / fmaxf(sqrtf(ss), 1e-8f);
    int q0 = (int)rintf(v.x * s), q1 = (int)rintf(v.y * s);
    int q2 = (int)rintf(v.z * s), q3 = (int)rintf(v.w * s);
    unsigned pk = (q0 & 0xFF) | ((q1 & 0xFF) << 8) |
                  ((q2 & 0xFF) << 16) | ((q3 & 0xFF) << 24);
    // lane holds k = 4*lane..4*lane+3 -> k0 = lane>>2, off = 4*(lane&3)
    *reinterpret_cast<unsigned*>(t8 + ((lane >> 2) << 9) + (r << 4) +
                                 ((lane & 3) << 2)) = pk;
  }
  __syncthreads();
  const uint4* ts = reinterpret_cast<const uint4*>(t8);
  uint4* outp = reinterpret_cast<uint4*>(dst + (size_t)pb * 8192);
  outp[threadIdx.x]       = ts[threadIdx.x];
  outp[threadIdx.x + 256] = ts[threadIdx.x + 256];
}

// ---------------------------------------------------------------------------
// 2) Fused GEMM + row-sum(exp2) -- i8 MFMA 32x32x32 (4404 TOPS, half the
//    MFMA instructions of 16x16x64).
//    R19 post-mortem: occupancy lever saturated (46%, time flat); counters
//    show MFMA (13.7us) + VALU (21.9us) + stalls ~= serial sum. Two wins
//    from the 32x32 shape at identical delivery machinery: 12% faster MFMA
//    pipe (17.4 -> 15.6us) and 2x fewer MFMA issue slots competing with the
//    VALU stream in the in-order wave.
//    Per wave per panel: one 32-col cluster = 8 MFMA (km=0..7, K=32 each),
//    16-elem exp2 epilogue. B-frag (lane l: col l&31, k=(l>>5)*16+e) reads
//    chunk (2km + (l>>5))*512 + (l&31)*16 of the k-major panel -> 1KB
//    contiguous per read, linear-in-lane, 0 conflicts (same property R4-R19).
//    A-frag: row l&31, k = km*32 + (l>>5)*16 (16B from row-major a8).
//    C layout (HW-verified m74/m101, dtype-indep): col=lane&31,
//    row=(reg&3)+8*(reg>>2)+4*(lane>>5) -> reduce = shfl_xor 1,2,4,8,16.
//    Ring-3 8KB panels (R16-proven), counted vmcnt(2)/0, ONE barrier/panel,
//    __launch_bounds__(256,5): regs ~60V+32A <= 102 cap; LDS 5x24KB=120KB.
//    Grid 64 rb (BM=128) x 32 cc. Tripwire: WRITE>>4MB = spill -> revert R19.
// ---------------------------------------------------------------------------
__global__ void __launch_bounds__(256, 5) fused_kernel(
    const char* __restrict__ a8, const char* __restrict__ p8,
    const char* __restrict__ n8, float* __restrict__ rowsum) {
  __shared__ __align__(16) char smem[3 * 8192];   // ring of 3 x 8KB panels
  const int tid  = threadIdx.x;
  const int lane = tid & 63;
  const int w    = tid >> 6;          // 0..3
  const int rb   = blockIdx.x >> 5;   // 0..63 (128 rows each)
  const int cc   = blockIdx.x & 31;   // 0..31 (512 cols = 16 panels each)
  const char* B = (cc < 16) ? (p8 + (size_t)cc * 16 * 8192)
                            : (n8 + (size_t)(cc - 16) * 16 * 8192);
  const int row0 = rb * 128 + w * 32;
  const int cr = lane & 31;           // col (B) / row (A) within fragment
  const int hi = lane >> 5;           // k-half selector
  const int vbase = (hi << 9) + (cr << 4);  // lane byte-offset within a panel

  // A fragments: 32 rows x K=256 i8 = 8 km x i32x4 (32 regs, pinned).
  // Lane l: row l&31, k = km*32 + (l>>5)*16 .. +15.
  i32x4 af[8];
#pragma unroll
  for (int km = 0; km < 8; ++km) {
    af[km] = *reinterpret_cast<const i32x4*>(
        a8 + (size_t)(row0 + cr) * DIM + km * 32 + hi * 16);
    asm volatile("" : "+v"(af[km]));   // non-remat def: stays resident
  }

  // Stage panel `p` (8KB contiguous) into ring slot `slot`: 2 loads/wave.
#define STAGE(slot, p)                                                         \
  {                                                                            \
    _Pragma("unroll")                                                          \
    for (int j = 0; j < 2; ++j) {                                              \
      const int L = (w << 1) | j;                                              \
      const char* src = B + ((size_t)(p) << 13) + (L << 10) + (lane << 4);     \
      char* dst = (char*)smem + ((slot) << 13) + (L << 10);                    \
      __builtin_amdgcn_global_load_lds(                                        \
          (const __attribute__((address_space(1))) void*)src,                  \
          (__attribute__((address_space(3))) void*)dst, 16, 0, 0);             \
    }                                                                          \
  }

#define MMI(A, Bf, C) __builtin_amdgcn_mfma_i32_32x32x32_i8((A), (Bf), (C), 0, 0, 0)

  float psum[16];
#pragma unroll
  for (int e = 0; e < 16; ++e) psum[e] = 0.f;
  const i32x16 zeroi = {0, 0, 0, 0, 0, 0, 0, 0, 0, 0, 0, 0, 0, 0, 0, 0};

  STAGE(0, 0);
  STAGE(1, 1);          // 4 loads/wave outstanding
  int rd = 0;           // slot of panel `it` (= it % 3)
  for (int it = 0; it < 16; ++it) {
    // Own panel-`it` loads done; panel it+1 stays in flight (counted).
    if (it <= 14) asm volatile("s_waitcnt vmcnt(2)" ::: "memory");
    else          asm volatile("s_waitcnt vmcnt(0)" ::: "memory");
    __builtin_amdgcn_s_barrier();
    const char* pbase = smem + (rd << 13) + vbase;
    const int st = (rd == 0) ? 2 : rd - 1;   // (it+2)%3 == (it-1)%3
    // km quad 0-3: B chunk base = km*1024 + vbase.
    i32x16 acc;
    {
      i32x4 b0 = *reinterpret_cast<const i32x4*>(pbase);
      i32x4 b1 = *reinterpret_cast<const i32x4*>(pbase + 1024);
      i32x4 b2 = *reinterpret_cast<const i32x4*>(pbase + 2048);
      i32x4 b3 = *reinterpret_cast<const i32x4*>(pbase + 3072);
      acc = MMI(af[0], b0, zeroi);
      acc = MMI(af[1], b1, acc);
      acc = MMI(af[2], b2, acc);
      acc = MMI(af[3], b3, acc);
    }
    if (it <= 13) STAGE(st, it + 2);   // slot of panel it-1: readers retired
    // km quad 4-7.
    {
      i32x4 b4 = *reinterpret_cast<const i32x4*>(pbase + 4096);
      i32x4 b5 = *reinterpret_cast<const i32x4*>(pbase + 5120);
      i32x4 b6 = *reinterpret_cast<const i32x4*>(pbase + 6144);
      i32x4 b7 = *reinterpret_cast<const i32x4*>(pbase + 7168);
      acc = MMI(af[4], b4, acc);
      acc = MMI(af[5], b5, acc);
      acc = MMI(af[6], b6, acc);
      acc = MMI(af[7], b7, acc);
    }
    // Epilogue: 16 exact i32 dots -> exp2 -> psum.
#pragma unroll
    for (int e = 0; e < 16; ++e)
      psum[e] += __builtin_amdgcn_exp2f((float)acc[e] * C2F);
    rd = (rd == 2) ? 0 : rd + 1;
  }

  // Reduce over the 32 column-lanes within each half-wave; accumulate per row.
  // C layout: col = lane&31, row = (e&3) + 8*(e>>2) + 4*hi.
#pragma unroll
  for (int e = 0; e < 16; ++e) {
    float s = psum[e];
    s += __shfl_xor(s, 1);
    s += __shfl_xor(s, 2);
    s += __shfl_xor(s, 4);
    s += __shfl_xor(s, 8);
    s += __shfl_xor(s, 16);
    if (cr == 0)
      atomicAdd(rowsum + row0 + (e & 3) + 8 * (e >> 2) + 4 * hi, s);
  }
#undef STAGE
#undef MMI
}

// ---------------------------------------------------------------------------
// 3) loss: grid 16 x 512 thr, one row per thread;
//    out[0] (+)= block-partials / N   (out zero-initialized in prep).
// ---------------------------------------------------------------------------
__global__ void __launch_bounds__(512) loss_kernel(
    const float* __restrict__ rowsum, const float* __restrict__ diag,
    float* __restrict__ out) {
  __shared__ float sh[8];
  int i = blockIdx.x * 512 + threadIdx.x;    // exactly covers 8192 rows
  float acc = logf(rowsum[i]) - diag[i];
#pragma unroll
  for (int m = 32; m; m >>= 1) acc += __shfl_xor(acc, m);
  if ((threadIdx.x & 63) == 0) sh[threadIdx.x >> 6] = acc;
  __syncthreads();
  if (threadIdx.x == 0) {
    float t = 0.f;
#pragma unroll
    for (int j = 0; j < 8; ++j) t += sh[j];
    atomicAdd(out, t / (float)N_ROWS);
  }
}

// ---------------------------------------------------------------------------
extern "C" void kernel_launch(void* const* d_in, const int* in_sizes, int n_in,
                              void* d_out, int out_size, void* d_ws, size_t ws_size,
                              hipStream_t stream) {
  const float* anc = (const float*)d_in[0];
  const float* pos = (const float*)d_in[1];
  const float* neg = (const float*)d_in[2];
  char* ws = (char*)d_ws;
  char* a8 = ws;                                  // [8192][256] i8 row-major
  char* p8 = ws + (size_t)N_ROWS * DIM;           // k-major i8 panels (2MB)
  char* n8 = p8 + (size_t)N_ROWS * DIM;
  float* diag = (float*)(ws + (size_t)3 * N_ROWS * DIM);  // 8192 f32
  float* rowsum = diag + N_ROWS;                          // 8192 f32
  float* out = (float*)d_out;

  prep_kernel<<<2048 + 512, 256, 0, stream>>>(anc, pos, neg, a8, p8, n8, diag, rowsum, out);
  fused_kernel<<<64 * 32, 256, 0, stream>>>(a8, p8, n8, rowsum);
  loss_kernel<<<16, 512, 0, stream>>>(rowsum, diag, out);
}

// Round 21
// 57.217 us; speedup vs baseline: 1.2387x; 1.2387x over previous
//
#include <hip/hip_runtime.h>
#include <hip/hip_bf16.h>

#define N_ROWS 8192
#define DIM 256
#define TEMP_INV 20.0f
// logit2 = cos * 20*log2(e); with int8 quantized (x127) operands the exact
// i32 dot is converted via C2F = 20*log2(e)/127^2, then exp2.
#define C2F 1.7889516e-3f

typedef __attribute__((ext_vector_type(4))) int i32x4;

// ---------------------------------------------------------------------------
// 1) Merged prep (int8 quantization) -- unchanged from R13/R16/R19 (proven).
// ---------------------------------------------------------------------------
__global__ void __launch_bounds__(256) prep_kernel(
    const float* __restrict__ anc, const float* __restrict__ pos,
    const float* __restrict__ neg, char* __restrict__ a8,
    char* __restrict__ p8, char* __restrict__ n8,
    float* __restrict__ diag, float* __restrict__ rowsum,
    float* __restrict__ out) {
  __shared__ __align__(16) char t8[8192];   // one k-major i8 panel
  const int lane = threadIdx.x & 63;
  const int w = threadIdx.x >> 6;

  if (blockIdx.x < 2048) {                   // ---- anchor rows ----
    int wid = blockIdx.x * 4 + w;            // row 0..8191
    float4 a = reinterpret_cast<const float4*>(anc + (size_t)wid * DIM)[lane];
    float4 p = reinterpret_cast<const float4*>(pos + (size_t)wid * DIM)[lane];
    float d  = a.x * p.x + a.y * p.y + a.z * p.z + a.w * p.w;
    float na = a.x * a.x + a.y * a.y + a.z * a.z + a.w * a.w;
    float np = p.x * p.x + p.y * p.y + p.z * p.z + p.w * p.w;
#pragma unroll
    for (int m = 32; m; m >>= 1) {
      d  += __shfl_xor(d, m);
      na += __shfl_xor(na, m);
      np += __shfl_xor(np, m);
    }
    float rna = fmaxf(sqrtf(na), 1e-8f);
    float s = 127.0f / rna;
    int q0 = (int)rintf(a.x * s), q1 = (int)rintf(a.y * s);
    int q2 = (int)rintf(a.z * s), q3 = (int)rintf(a.w * s);
    unsigned pk = (q0 & 0xFF) | ((q1 & 0xFF) << 8) |
                  ((q2 & 0xFF) << 16) | ((q3 & 0xFF) << 24);
    *reinterpret_cast<unsigned*>(a8 + (size_t)wid * DIM + (lane << 2)) = pk;
    if (lane == 0) {
      diag[wid] = TEMP_INV * d / (rna * fmaxf(sqrtf(np), 1e-8f));
      rowsum[wid] = 0.f;
    }
    return;
  }
  // ---- P/N k-major i8 panels ----
  const int b = blockIdx.x - 2048;           // 0..511
  if (b == 511 && threadIdx.x == 0) out[0] = 0.f;
  const float* src = (b < 256) ? pos : neg;
  char* dst = (b < 256) ? p8 : n8;
  const int pb = b & 255;
#pragma unroll
  for (int i = 0; i < 8; ++i) {
    int r = i * 4 + w;                       // row (col of B) within panel
    float4 v = reinterpret_cast<const float4*>(src + (size_t)(pb * 32 + r) * DIM)[lane];
    float ss = v.x * v.x + v.y * v.y + v.z * v.z + v.w * v.w;
#pragma unroll
    for (int m = 32; m; m >>= 1) ss += __shfl_xor(ss, m);
    float s = 127.0f / fmaxf(sqrtf(ss), 1e-8f);
    int q0 = (int)rintf(v.x * s), q1 = (int)rintf(v.y * s);
    int q2 = (int)rintf(v.z * s), q3 = (int)rintf(v.w * s);
    unsigned pk = (q0 & 0xFF) | ((q1 & 0xFF) << 8) |
                  ((q2 & 0xFF) << 16) | ((q3 & 0xFF) << 24);
    // lane holds k = 4*lane..4*lane+3 -> k0 = lane>>2, off = 4*(lane&3)
    *reinterpret_cast<unsigned*>(t8 + ((lane >> 2) << 9) + (r << 4) +
                                 ((lane & 3) << 2)) = pk;
  }
  __syncthreads();
  const uint4* ts = reinterpret_cast<const uint4*>(t8);
  uint4* outp = reinterpret_cast<uint4*>(dst + (size_t)pb * 8192);
  outp[threadIdx.x]       = ts[threadIdx.x];
  outp[threadIdx.x + 256] = ts[threadIdx.x + 256];
}

// ---------------------------------------------------------------------------
// 2) Fused GEMM + row-sum(exp2) -- R19's exact kernel (best measured).
//    R20 post-mortem: 32x32x32 regressed (serially-dependent 8-MFMA chain
//    into one 16-reg accumulator exposed MFMA latency; fewer, bigger ops
//    scheduled worse in the in-order wave). Reverted per R19 pre-commit.
//    Config: i8 16x16x64 MFMA, 32-row waves (af = 2rf x 4km = 32 regs
//    pinned), ring-3 8KB k-major panels (24KB LDS), counted vmcnt(2)/0,
//    ONE barrier/panel, __launch_bounds__(256,6) (40 VGPR compiled, ~46%
//    occupancy), grid 64 rb x 32 cc. ds_reads linear-in-lane -> 0 bank
//    conflicts (verified R4-R20). Exact i32 dot; epilogue exp2f(acc*C2F).
//    MFMA C layout (shape-determined, verified): col=lane&15, row=(lane>>4)*4+q.
// ---------------------------------------------------------------------------
__global__ void __launch_bounds__(256, 6) fused_kernel(
    const char* __restrict__ a8, const char* __restrict__ p8,
    const char* __restrict__ n8, float* __restrict__ rowsum) {
  __shared__ __align__(16) char smem[3 * 8192];   // ring of 3 x 8KB panels
  const int tid  = threadIdx.x;
  const int lane = tid & 63;
  const int w    = tid >> 6;          // 0..3
  const int rb   = blockIdx.x >> 5;   // 0..63 (128 rows each)
  const int cc   = blockIdx.x & 31;   // 0..31 (512 cols = 16 panels each)
  const char* B = (cc < 16) ? (p8 + (size_t)cc * 16 * 8192)
                            : (n8 + (size_t)(cc - 16) * 16 * 8192);
  const int row0 = rb * 128 + w * 32;
  const int ar = lane & 15;           // fragment row/col index
  const int g  = lane >> 4;           // k-group within fragment
  const int vbase = (g << 9) + (ar << 4);  // lane byte-offset within a panel

  // A fragments: 32 rows x K=256 i8 = 2rf x 4km x i32x4 (32 regs, pinned).
  i32x4 af[2][4];
#pragma unroll
  for (int rf = 0; rf < 2; ++rf)
#pragma unroll
    for (int km = 0; km < 4; ++km) {
      af[rf][km] = *reinterpret_cast<const i32x4*>(
          a8 + (size_t)(row0 + rf * 16 + ar) * DIM + km * 64 + g * 16);
      asm volatile("" : "+v"(af[rf][km]));   // non-remat def: stays resident
    }

  // Stage panel `p` (8KB contiguous) into ring slot `slot`: 2 loads/wave.
#define STAGE(slot, p)                                                         \
  {                                                                            \
    _Pragma("unroll")                                                          \
    for (int j = 0; j < 2; ++j) {                                              \
      const int L = (w << 1) | j;                                              \
      const char* src = B + ((size_t)(p) << 13) + (L << 10) + (lane << 4);     \
      char* dst = (char*)smem + ((slot) << 13) + (L << 10);                    \
      __builtin_amdgcn_global_load_lds(                                        \
          (const __attribute__((address_space(1))) void*)src,                  \
          (__attribute__((address_space(3))) void*)dst, 16, 0, 0);             \
    }                                                                          \
  }

#define MMI(A, Bf, C) __builtin_amdgcn_mfma_i32_16x16x64_i8((A), (Bf), (C), 0, 0, 0)

  // One cf-cluster: 4 ds_read_b128 + 8 MFMA + 8-elem exp2 epilogue.
#define CLUSTER(CFOFF)                                                         \
  {                                                                            \
    i32x4 bf[4];                                                               \
    _Pragma("unroll")                                                          \
    for (int km = 0; km < 4; ++km)                                             \
      bf[km] = *reinterpret_cast<const i32x4*>(pbase + (km << 11) + (CFOFF));  \
    i32x4 acc[2];                                                              \
    _Pragma("unroll")                                                          \
    for (int rf = 0; rf < 2; ++rf) acc[rf] = MMI(af[rf][0], bf[0], zeroi);     \
    _Pragma("unroll")                                                          \
    for (int km = 1; km < 4; ++km)                                             \
      _Pragma("unroll")                                                        \
      for (int rf = 0; rf < 2; ++rf)                                           \
        acc[rf] = MMI(af[rf][km], bf[km], acc[rf]);                            \
    _Pragma("unroll")                                                          \
    for (int rf = 0; rf < 2; ++rf)                                             \
      _Pragma("unroll")                                                        \
      for (int q = 0; q < 4; ++q)                                              \
        psum[rf][q] += __builtin_amdgcn_exp2f((float)acc[rf][q] * C2F);        \
  }

  float psum[2][4];
#pragma unroll
  for (int rf = 0; rf < 2; ++rf)
#pragma unroll
    for (int q = 0; q < 4; ++q) psum[rf][q] = 0.f;
  const i32x4 zeroi = {0, 0, 0, 0};

  STAGE(0, 0);
  STAGE(1, 1);          // 4 loads/wave outstanding
  int rd = 0;           // slot of panel `it` (= it % 3)
  for (int it = 0; it < 16; ++it) {
    // Own panel-`it` loads done; panel it+1 stays in flight (counted).
    if (it <= 14) asm volatile("s_waitcnt vmcnt(2)" ::: "memory");
    else          asm volatile("s_waitcnt vmcnt(0)" ::: "memory");
    __builtin_amdgcn_s_barrier();
    const char* pbase = smem + (rd << 13) + vbase;
    const int st = (rd == 0) ? 2 : rd - 1;   // (it+2)%3 == (it-1)%3
    CLUSTER(0);                        // cf0 (cols ar)
    if (it <= 13) STAGE(st, it + 2);   // slot of panel it-1: readers retired
    CLUSTER(256);                      // cf1 (cols 16+ar)
    rd = (rd == 2) ? 0 : rd + 1;
  }

  // Reduce over the 16 column-lanes (vary ar, keep g); accumulate per row.
#pragma unroll
  for (int rf = 0; rf < 2; ++rf)
#pragma unroll
    for (int q = 0; q < 4; ++q) {
      float s = psum[rf][q];
      s += __shfl_xor(s, 1);
      s += __shfl_xor(s, 2);
      s += __shfl_xor(s, 4);
      s += __shfl_xor(s, 8);
      if (ar == 0)
        atomicAdd(rowsum + row0 + rf * 16 + g * 4 + q, s);
    }
#undef STAGE
#undef CLUSTER
#undef MMI
}

// ---------------------------------------------------------------------------
// 3) loss: grid 16 x 512 thr, one row per thread;
//    out[0] (+)= block-partials / N   (out zero-initialized in prep).
// ---------------------------------------------------------------------------
__global__ void __launch_bounds__(512) loss_kernel(
    const float* __restrict__ rowsum, const float* __restrict__ diag,
    float* __restrict__ out) {
  __shared__ float sh[8];
  int i = blockIdx.x * 512 + threadIdx.x;    // exactly covers 8192 rows
  float acc = logf(rowsum[i]) - diag[i];
#pragma unroll
  for (int m = 32; m; m >>= 1) acc += __shfl_xor(acc, m);
  if ((threadIdx.x & 63) == 0) sh[threadIdx.x >> 6] = acc;
  __syncthreads();
  if (threadIdx.x == 0) {
    float t = 0.f;
#pragma unroll
    for (int j = 0; j < 8; ++j) t += sh[j];
    atomicAdd(out, t / (float)N_ROWS);
  }
}

// ---------------------------------------------------------------------------
extern "C" void kernel_launch(void* const* d_in, const int* in_sizes, int n_in,
                              void* d_out, int out_size, void* d_ws, size_t ws_size,
                              hipStream_t stream) {
  const float* anc = (const float*)d_in[0];
  const float* pos = (const float*)d_in[1];
  const float* neg = (const float*)d_in[2];
  char* ws = (char*)d_ws;
  char* a8 = ws;                                  // [8192][256] i8 row-major
  char* p8 = ws + (size_t)N_ROWS * DIM;           // k-major i8 panels (2MB)
  char* n8 = p8 + (size_t)N_ROWS * DIM;
  float* diag = (float*)(ws + (size_t)3 * N_ROWS * DIM);  // 8192 f32
  float* rowsum = diag + N_ROWS;                          // 8192 f32
  float* out = (float*)d_out;

  prep_kernel<<<2048 + 512, 256, 0, stream>>>(anc, pos, neg, a8, p8, n8, diag, rowsum, out);
  fused_kernel<<<64 * 32, 256, 0, stream>>>(a8, p8, n8, rowsum);
  loss_kernel<<<16, 512, 0, stream>>>(rowsum, diag, out);
}